// Round 10
// baseline (178.791 us; speedup 1.0000x reference)
//
#include <hip/hip_runtime.h>
#include <hip/hip_bf16.h>
#include <math.h>

#define B 128
#define V 32
#define H 128
#define LDH 264    // h-region row pitch in bf16 elems (528 B)
#define NTHR 256

typedef __attribute__((ext_vector_type(8))) short bf16x8;
typedef __attribute__((ext_vector_type(4))) float f32x4;

// Swapped-operand layout: D = W_frag x Act_frag; lane owns batch row (lane&15)
// and 4 consecutive units ((lane>>4)*4 + reg).
__device__ inline f32x4 mfma_wx(bf16x8 wf, bf16x8 xf, f32x4 c) {
    return __builtin_amdgcn_mfma_f32_16x16x32_bf16(wf, xf, c, 0, 0, 0);
}
__device__ inline unsigned short f2bf(float f) {
    __hip_bfloat16 h = __float2bfloat16(f);
    return __builtin_bit_cast(unsigned short, h);
}
__device__ inline float bf2f(unsigned short u) {
    unsigned int x = ((unsigned int)u) << 16;
    return __builtin_bit_cast(float, x);
}
// pre-scaled activations: weights/biases for r,z carry -1/ln2, n carries 2/ln2
__device__ inline float sig_pre(float y)  { return __builtin_amdgcn_rcpf(1.f + __builtin_amdgcn_exp2f(y)); }
__device__ inline float tanh_pre(float y) { return 1.f - 2.f * __builtin_amdgcn_rcpf(__builtin_amdgcn_exp2f(y) + 1.f); }
__device__ inline bf16x8 load_xfrag(const float* p) {
    float4 a = *(const float4*)p;
    float4 b = *(const float4*)(p + 4);
    bf16x8 r;
    r[0] = (short)f2bf(a.x); r[1] = (short)f2bf(a.y);
    r[2] = (short)f2bf(a.z); r[3] = (short)f2bf(a.w);
    r[4] = (short)f2bf(b.x); r[5] = (short)f2bf(b.y);
    r[6] = (short)f2bf(b.z); r[7] = (short)f2bf(b.w);
    return r;
}
__device__ inline uint2 pack4(float a, float b, float c, float d) {
    uint2 r;
    r.x = (unsigned int)f2bf(a) | ((unsigned int)f2bf(b) << 16);
    r.y = (unsigned int)f2bf(c) | ((unsigned int)f2bf(d) << 16);
    return r;
}

// ---------------------------------------------------------------------------
// Pack GRU weights (PRE-SCALED) + proj weights into MFMA fragment order.
// ---------------------------------------------------------------------------
__global__ void prep_pack(const float* __restrict__ wir_w, const float* __restrict__ whr_w,
                          const float* __restrict__ wiz_w, const float* __restrict__ whz_w,
                          const float* __restrict__ win_w, const float* __restrict__ whn_w,
                          const float* __restrict__ wir_b, const float* __restrict__ whr_b,
                          const float* __restrict__ wiz_b, const float* __restrict__ whz_b,
                          const float* __restrict__ win_b, const float* __restrict__ whn_b,
                          const float* __restrict__ mu_w, const float* __restrict__ mu_b,
                          const float* __restrict__ lv_w, const float* __restrict__ lv_b,
                          unsigned short* __restrict__ wFrag, unsigned short* __restrict__ pFrag,
                          float* __restrict__ bias)
{
    int idx = blockIdx.x * blockDim.x + threadIdx.x;
    if (idx < 13824) {
        int lane = idx & 63;
        int ctks = idx >> 6;
        int ct = ctks % 24;
        int ks = ctks / 24;
        int g = ct >> 3;
        int t = ct & 7;
        int u = t * 16 + (lane & 15);
        const float scl = (g == 2) ? 2.88539008f : -1.44269504f;
        const float* wi = (g == 0) ? wir_w : (g == 1) ? wiz_w : win_w;
        const float* wh = (g == 0) ? whr_w : (g == 1) ? whz_w : whn_w;
        unsigned short v[8] __attribute__((aligned(16)));
        #pragma unroll
        for (int i = 0; i < 8; ++i) {
            float f;
            if (ks == 0) { int k = 8 * (lane >> 4) + i; f = wi[u * V + k]; }
            else         { int k = (ks - 1) * 32 + 8 * (lane >> 4) + i; f = wh[u * 256 + k]; }
            v[i] = f2bf(f * scl);
        }
        *(int4*)(wFrag + (size_t)idx * 8) = *(const int4*)v;
    } else if (idx < 13824 + 4096) {
        int pidx = idx - 13824;
        int lane = pidx & 63;
        int rest = pidx >> 6;
        int ct2 = rest & 15;
        int ks = rest >> 4;
        int sel = ct2 >> 3, tl = ct2 & 7;
        int u = tl * 16 + (lane & 15);
        const float* wsrc = sel ? lv_w : mu_w;
        unsigned short v[8] __attribute__((aligned(16)));
        #pragma unroll
        for (int i = 0; i < 8; ++i) {
            int k = ks * 32 + 8 * (lane >> 4) + i;
            v[i] = f2bf(wsrc[u * H + k]);
        }
        *(int4*)(pFrag + (size_t)pidx * 8) = *(const int4*)v;
    }
    if (idx < 6 * H) {
        int s = idx / H, u = idx % H;
        float val;
        if (s == 0)      val = (wir_b[u] + whr_b[u]) * -1.44269504f;
        else if (s == 1) val = (wiz_b[u] + whz_b[u]) * -1.44269504f;
        else if (s == 2) val = win_b[u] * 2.88539008f;
        else if (s == 3) val = whn_b[u] * 2.88539008f;
        else if (s == 4) val = mu_b[u];
        else             val = lv_b[u];
        bias[idx] = val;
    }
}

// ---------------------------------------------------------------------------
// Fused subtree kernel: levels leaf+9+8. Grid 1024: block (n = d8 node, q =
// 32-row chunk). Per block: 2 x {leafpair -> d9 (out to LDS only)}, then d8.
// lvl9 never touches HBM.
// ---------------------------------------------------------------------------
__global__ __launch_bounds__(NTHR, 4) void subtree8_kernel(
    const float* __restrict__ targets, const float* __restrict__ masks,
    unsigned short* __restrict__ lvl8,
    const unsigned short* __restrict__ wFrag, const float* __restrict__ bias)
{
    __shared__ __attribute__((aligned(16))) unsigned short h_lds[32 * LDH];   // leaf h of current d9 node
    __shared__ __attribute__((aligned(16))) unsigned short h2_lds[32 * LDH];  // d9 outputs [h(2n)|h(2n+1)]

    const int tid = threadIdx.x;
    const int lane = tid & 63;
    const int w = tid >> 6;
    const int l15 = lane & 15;
    const int lg = lane >> 4;
    const int n = blockIdx.x >> 2;
    const int q = blockIdx.x & 3;

    // K0 (input) weight frags — used by leaf, d9-K0, d8-K0
    bf16x8 w0[2][3];
    #pragma unroll
    for (int t = 0; t < 2; ++t)
        #pragma unroll
        for (int g = 0; g < 3; ++g)
            w0[t][g] = *(const bf16x8*)(wFrag + (((size_t)g * 8 + 2 * w + t) * 64 + lane) * 8);

    f32x4 b_r[2], b_z[2], b_in[2], b_hn[2];
    #pragma unroll
    for (int t = 0; t < 2; ++t) {
        int u0 = w * 32 + t * 16 + lg * 4;
        b_r[t]  = *(const f32x4*)(bias + u0);
        b_z[t]  = *(const f32x4*)(bias + 128 + u0);
        b_in[t] = *(const f32x4*)(bias + 256 + u0);
        b_hn[t] = *(const f32x4*)(bias + 384 + u0);
    }

    // d8 x frags (used at the end)
    const size_t r8 = (size_t)(255 + n) * B + (size_t)q * 32;
    bf16x8 x8_0 = load_xfrag(targets + (r8 + l15) * V + 8 * lg);
    bf16x8 x8_1 = load_xfrag(targets + (r8 + 16 + l15) * V + 8 * lg);

    for (int half = 0; half < 2; ++half) {
        const int j = 2 * n + half;                         // d9 node
        const size_t r9 = (size_t)(511 + j) * B + (size_t)q * 32;
        bf16x8 x9_0 = load_xfrag(targets + (r9 + l15) * V + 8 * lg);
        bf16x8 x9_1 = load_xfrag(targets + (r9 + 16 + l15) * V + 8 * lg);

        // ---- leaf children of j -> h_lds ----
        #pragma unroll
        for (int c = 0; c < 2; ++c) {
            const size_t crow = (size_t)(1023 + 2 * j + c) * B + (size_t)q * 32;
            bf16x8 xf0 = load_xfrag(targets + (crow + l15) * V + 8 * lg);
            bf16x8 xf1 = load_xfrag(targets + (crow + 16 + l15) * V + 8 * lg);
            f32x4 ar[2][2], az[2][2], an[2][2];
            #pragma unroll
            for (int t = 0; t < 2; ++t) {
                ar[0][t] = b_r[t];  ar[1][t] = b_r[t];
                az[0][t] = b_z[t];  az[1][t] = b_z[t];
                an[0][t] = b_in[t]; an[1][t] = b_in[t];
            }
            #pragma unroll
            for (int t = 0; t < 2; ++t) {
                ar[0][t] = mfma_wx(w0[t][0], xf0, ar[0][t]);
                ar[1][t] = mfma_wx(w0[t][0], xf1, ar[1][t]);
                az[0][t] = mfma_wx(w0[t][1], xf0, az[0][t]);
                az[1][t] = mfma_wx(w0[t][1], xf1, az[1][t]);
                an[0][t] = mfma_wx(w0[t][2], xf0, an[0][t]);
                an[1][t] = mfma_wx(w0[t][2], xf1, an[1][t]);
            }
            #pragma unroll
            for (int rt = 0; rt < 2; ++rt) {
                int row = rt * 16 + l15;
                float m = masks[crow + row];
                #pragma unroll
                for (int t = 0; t < 2; ++t) {
                    int u0 = w * 32 + t * 16 + lg * 4;
                    float ho[4];
                    #pragma unroll
                    for (int reg = 0; reg < 4; ++reg) {
                        float rg = sig_pre(ar[rt][t][reg]);
                        float zg = sig_pre(az[rt][t][reg]);
                        float cg = tanh_pre(an[rt][t][reg] + rg * b_hn[t][reg]);
                        ho[reg] = (cg - zg * cg) * m;
                    }
                    *(uint2*)(&h_lds[row * LDH + c * 128 + u0]) = pack4(ho[0], ho[1], ho[2], ho[3]);
                }
            }
        }
        __syncthreads();   // h_lds (leaf h) ready

        // ---- d9 tile: MFMA from h_lds ----
        f32x4 acc_r[2][2], acc_z[2][2], acc_in[2][2], acc_hn[2][2];
        #pragma unroll
        for (int t = 0; t < 2; ++t) {
            acc_r[0][t] = b_r[t];   acc_r[1][t] = b_r[t];
            acc_z[0][t] = b_z[t];   acc_z[1][t] = b_z[t];
            acc_in[0][t] = b_in[t]; acc_in[1][t] = b_in[t];
            acc_hn[0][t] = b_hn[t]; acc_hn[1][t] = b_hn[t];
        }
        #pragma unroll
        for (int t = 0; t < 2; ++t) {
            acc_r[0][t] = mfma_wx(w0[t][0], x9_0, acc_r[0][t]);
            acc_r[1][t] = mfma_wx(w0[t][0], x9_1, acc_r[1][t]);
            acc_z[0][t] = mfma_wx(w0[t][1], x9_0, acc_z[0][t]);
            acc_z[1][t] = mfma_wx(w0[t][1], x9_1, acc_z[1][t]);
            acc_in[0][t] = mfma_wx(w0[t][2], x9_0, acc_in[0][t]);
            acc_in[1][t] = mfma_wx(w0[t][2], x9_1, acc_in[1][t]);
        }
        #pragma unroll 2
        for (int ks = 1; ks <= 8; ++ks) {
            bf16x8 a0 = *(const bf16x8*)(&h_lds[l15 * LDH + (ks - 1) * 32 + 8 * lg]);
            bf16x8 a1 = *(const bf16x8*)(&h_lds[(16 + l15) * LDH + (ks - 1) * 32 + 8 * lg]);
            size_t fb = (size_t)ks * 24 * 64;
            #pragma unroll
            for (int t = 0; t < 2; ++t) {
                int tt = 2 * w + t;
                bf16x8 wr_ = *(const bf16x8*)(wFrag + (fb + (size_t)(tt) * 64 + lane) * 8);
                bf16x8 wz_ = *(const bf16x8*)(wFrag + (fb + (size_t)(8 + tt) * 64 + lane) * 8);
                bf16x8 wn_ = *(const bf16x8*)(wFrag + (fb + (size_t)(16 + tt) * 64 + lane) * 8);
                acc_r[0][t] = mfma_wx(wr_, a0, acc_r[0][t]);
                acc_r[1][t] = mfma_wx(wr_, a1, acc_r[1][t]);
                acc_z[0][t] = mfma_wx(wz_, a0, acc_z[0][t]);
                acc_z[1][t] = mfma_wx(wz_, a1, acc_z[1][t]);
                acc_hn[0][t] = mfma_wx(wn_, a0, acc_hn[0][t]);
                acc_hn[1][t] = mfma_wx(wn_, a1, acc_hn[1][t]);
            }
        }
        // pre-read h1/h2 (leaf h) into regs BEFORE releasing h_lds
        ushort4 h1v[2][2], h2v[2][2];
        #pragma unroll
        for (int rt = 0; rt < 2; ++rt) {
            int row = rt * 16 + l15;
            #pragma unroll
            for (int t = 0; t < 2; ++t) {
                int u0 = w * 32 + t * 16 + lg * 4;
                h1v[rt][t] = *(const ushort4*)(&h_lds[row * LDH + u0]);
                h2v[rt][t] = *(const ushort4*)(&h_lds[row * LDH + 128 + u0]);
            }
        }
        __syncthreads();   // all h_lds reads done; next half may overwrite

        // ---- d9 epilogue -> h2_lds only ----
        #pragma unroll
        for (int rt = 0; rt < 2; ++rt) {
            int row = rt * 16 + l15;
            float m = masks[r9 + row];
            #pragma unroll
            for (int t = 0; t < 2; ++t) {
                int u0 = w * 32 + t * 16 + lg * 4;
                const unsigned short* h1p = (const unsigned short*)&h1v[rt][t];
                const unsigned short* h2p = (const unsigned short*)&h2v[rt][t];
                float ho[4];
                #pragma unroll
                for (int reg = 0; reg < 4; ++reg) {
                    float rg = sig_pre(acc_r[rt][t][reg]);
                    float zg = sig_pre(acc_z[rt][t][reg]);
                    float cg = tanh_pre(acc_in[rt][t][reg] + rg * acc_hn[rt][t][reg]);
                    float hm = 0.5f * bf2f(h1p[reg]) + 0.5f * bf2f(h2p[reg]);
                    ho[reg] = (cg + zg * (hm - cg)) * m;
                }
                *(uint2*)(&h2_lds[row * LDH + half * 128 + u0]) = pack4(ho[0], ho[1], ho[2], ho[3]);
            }
        }
    }
    __syncthreads();   // h2_lds (both d9 nodes) ready

    // ---- d8 tile: x8 regs + h2_lds -> global lvl8 ----
    {
        f32x4 acc_r[2][2], acc_z[2][2], acc_in[2][2], acc_hn[2][2];
        #pragma unroll
        for (int t = 0; t < 2; ++t) {
            acc_r[0][t] = b_r[t];   acc_r[1][t] = b_r[t];
            acc_z[0][t] = b_z[t];   acc_z[1][t] = b_z[t];
            acc_in[0][t] = b_in[t]; acc_in[1][t] = b_in[t];
            acc_hn[0][t] = b_hn[t]; acc_hn[1][t] = b_hn[t];
        }
        #pragma unroll
        for (int t = 0; t < 2; ++t) {
            acc_r[0][t] = mfma_wx(w0[t][0], x8_0, acc_r[0][t]);
            acc_r[1][t] = mfma_wx(w0[t][0], x8_1, acc_r[1][t]);
            acc_z[0][t] = mfma_wx(w0[t][1], x8_0, acc_z[0][t]);
            acc_z[1][t] = mfma_wx(w0[t][1], x8_1, acc_z[1][t]);
            acc_in[0][t] = mfma_wx(w0[t][2], x8_0, acc_in[0][t]);
            acc_in[1][t] = mfma_wx(w0[t][2], x8_1, acc_in[1][t]);
        }
        #pragma unroll 2
        for (int ks = 1; ks <= 8; ++ks) {
            bf16x8 a0 = *(const bf16x8*)(&h2_lds[l15 * LDH + (ks - 1) * 32 + 8 * lg]);
            bf16x8 a1 = *(const bf16x8*)(&h2_lds[(16 + l15) * LDH + (ks - 1) * 32 + 8 * lg]);
            size_t fb = (size_t)ks * 24 * 64;
            #pragma unroll
            for (int t = 0; t < 2; ++t) {
                int tt = 2 * w + t;
                bf16x8 wr_ = *(const bf16x8*)(wFrag + (fb + (size_t)(tt) * 64 + lane) * 8);
                bf16x8 wz_ = *(const bf16x8*)(wFrag + (fb + (size_t)(8 + tt) * 64 + lane) * 8);
                bf16x8 wn_ = *(const bf16x8*)(wFrag + (fb + (size_t)(16 + tt) * 64 + lane) * 8);
                acc_r[0][t] = mfma_wx(wr_, a0, acc_r[0][t]);
                acc_r[1][t] = mfma_wx(wr_, a1, acc_r[1][t]);
                acc_z[0][t] = mfma_wx(wz_, a0, acc_z[0][t]);
                acc_z[1][t] = mfma_wx(wz_, a1, acc_z[1][t]);
                acc_hn[0][t] = mfma_wx(wn_, a0, acc_hn[0][t]);
                acc_hn[1][t] = mfma_wx(wn_, a1, acc_hn[1][t]);
            }
        }
        #pragma unroll
        for (int rt = 0; rt < 2; ++rt) {
            int row = rt * 16 + l15;
            float m = masks[r8 + row];
            #pragma unroll
            for (int t = 0; t < 2; ++t) {
                int u0 = w * 32 + t * 16 + lg * 4;
                ushort4 h1v = *(const ushort4*)(&h2_lds[row * LDH + u0]);
                ushort4 h2v = *(const ushort4*)(&h2_lds[row * LDH + 128 + u0]);
                const unsigned short* h1p = (const unsigned short*)&h1v;
                const unsigned short* h2p = (const unsigned short*)&h2v;
                float ho[4];
                #pragma unroll
                for (int reg = 0; reg < 4; ++reg) {
                    float rg = sig_pre(acc_r[rt][t][reg]);
                    float zg = sig_pre(acc_z[rt][t][reg]);
                    float cg = tanh_pre(acc_in[rt][t][reg] + rg * acc_hn[rt][t][reg]);
                    float hm = 0.5f * bf2f(h1p[reg]) + 0.5f * bf2f(h2p[reg]);
                    ho[reg] = (cg + zg * (hm - cg)) * m;
                }
                *(uint2*)(lvl8 + ((size_t)n * B + (size_t)q * 32 + row) * H + u0) =
                    pack4(ho[0], ho[1], ho[2], ho[3]);
            }
        }
    }
}

// ---------------------------------------------------------------------------
// Pair kernel: (du, dl=du-1) + optional fused projection at dl==0. (unchanged)
// ---------------------------------------------------------------------------
__global__ __launch_bounds__(NTHR, 4) void pair_kernel(
    const float* __restrict__ targets, const float* __restrict__ masks,
    int du,
    const unsigned short* __restrict__ prev,
    unsigned short* __restrict__ outl,
    const unsigned short* __restrict__ wFrag, const float* __restrict__ bias,
    int do_proj, const unsigned short* __restrict__ pFrag, float* __restrict__ proj_out)
{
    __shared__ __attribute__((aligned(16))) unsigned short hc[32 * LDH];
    __shared__ __attribute__((aligned(16))) unsigned short hp[16 * LDH];

    const int tid = threadIdx.x;
    const int lane = tid & 63;
    const int w = tid >> 6;
    const int l15 = lane & 15;
    const int lg = lane >> 4;
    const int p = blockIdx.x >> 3;
    const int c8 = blockIdx.x & 7;
    const int dl = du - 1;

    #pragma unroll
    for (int t = 0; t < 4; ++t) {
        int task = t * NTHR + tid;
        int row = task >> 5;
        int ck = task & 31;
        int gnode = 4 * p + ((row >> 4) << 1) + (ck >> 4);
        int4 v = *(const int4*)(prev + (((size_t)gnode) * B + (size_t)c8 * 16 + (row & 15)) * H + (ck & 15) * 8);
        *(int4*)(&hc[row * LDH + ck * 8]) = v;
    }
    const size_t cbase = (size_t)((1 << du) - 1) + 2 * p;
    bf16x8 xc0 = load_xfrag(targets + ((cbase) * B + (size_t)c8 * 16 + l15) * V + 8 * lg);
    bf16x8 xc1 = load_xfrag(targets + ((cbase + 1) * B + (size_t)c8 * 16 + l15) * V + 8 * lg);
    const size_t pnode = (size_t)((1 << dl) - 1) + p;
    bf16x8 xp = load_xfrag(targets + (pnode * B + (size_t)c8 * 16 + l15) * V + 8 * lg);

    f32x4 b_r[2], b_z[2], b_in[2], b_hn[2];
    #pragma unroll
    for (int t = 0; t < 2; ++t) {
        int u0 = w * 32 + t * 16 + lg * 4;
        b_r[t]  = *(const f32x4*)(bias + u0);
        b_z[t]  = *(const f32x4*)(bias + 128 + u0);
        b_in[t] = *(const f32x4*)(bias + 256 + u0);
        b_hn[t] = *(const f32x4*)(bias + 384 + u0);
    }
    __syncthreads();

    // ---- children (rt = child index, 16 rows each) ----
    {
        f32x4 acc_r[2][2], acc_z[2][2], acc_in[2][2], acc_hn[2][2];
        #pragma unroll
        for (int t = 0; t < 2; ++t) {
            acc_r[0][t] = b_r[t];   acc_r[1][t] = b_r[t];
            acc_z[0][t] = b_z[t];   acc_z[1][t] = b_z[t];
            acc_in[0][t] = b_in[t]; acc_in[1][t] = b_in[t];
            acc_hn[0][t] = b_hn[t]; acc_hn[1][t] = b_hn[t];
        }
        #pragma unroll
        for (int t = 0; t < 2; ++t) {
            int tt = 2 * w + t;
            bf16x8 wr_ = *(const bf16x8*)(wFrag + ((size_t)(tt) * 64 + lane) * 8);
            bf16x8 wz_ = *(const bf16x8*)(wFrag + ((size_t)(8 + tt) * 64 + lane) * 8);
            bf16x8 wn_ = *(const bf16x8*)(wFrag + ((size_t)(16 + tt) * 64 + lane) * 8);
            acc_r[0][t] = mfma_wx(wr_, xc0, acc_r[0][t]);
            acc_r[1][t] = mfma_wx(wr_, xc1, acc_r[1][t]);
            acc_z[0][t] = mfma_wx(wz_, xc0, acc_z[0][t]);
            acc_z[1][t] = mfma_wx(wz_, xc1, acc_z[1][t]);
            acc_in[0][t] = mfma_wx(wn_, xc0, acc_in[0][t]);
            acc_in[1][t] = mfma_wx(wn_, xc1, acc_in[1][t]);
        }
        #pragma unroll 2
        for (int ks = 1; ks <= 8; ++ks) {
            bf16x8 a0 = *(const bf16x8*)(&hc[l15 * LDH + (ks - 1) * 32 + 8 * lg]);
            bf16x8 a1 = *(const bf16x8*)(&hc[(16 + l15) * LDH + (ks - 1) * 32 + 8 * lg]);
            size_t fb = (size_t)ks * 24 * 64;
            #pragma unroll
            for (int t = 0; t < 2; ++t) {
                int tt = 2 * w + t;
                bf16x8 wr_ = *(const bf16x8*)(wFrag + (fb + (size_t)(tt) * 64 + lane) * 8);
                bf16x8 wz_ = *(const bf16x8*)(wFrag + (fb + (size_t)(8 + tt) * 64 + lane) * 8);
                bf16x8 wn_ = *(const bf16x8*)(wFrag + (fb + (size_t)(16 + tt) * 64 + lane) * 8);
                acc_r[0][t] = mfma_wx(wr_, a0, acc_r[0][t]);
                acc_r[1][t] = mfma_wx(wr_, a1, acc_r[1][t]);
                acc_z[0][t] = mfma_wx(wz_, a0, acc_z[0][t]);
                acc_z[1][t] = mfma_wx(wz_, a1, acc_z[1][t]);
                acc_hn[0][t] = mfma_wx(wn_, a0, acc_hn[0][t]);
                acc_hn[1][t] = mfma_wx(wn_, a1, acc_hn[1][t]);
            }
        }
        #pragma unroll
        for (int rt = 0; rt < 2; ++rt) {
            float m = masks[(cbase + rt) * B + (size_t)c8 * 16 + l15];
            int hrow = rt * 16 + l15;
            #pragma unroll
            for (int t = 0; t < 2; ++t) {
                int u0 = w * 32 + t * 16 + lg * 4;
                ushort4 h1v = *(const ushort4*)(&hc[hrow * LDH + u0]);
                ushort4 h2v = *(const ushort4*)(&hc[hrow * LDH + 128 + u0]);
                const unsigned short* h1p = (const unsigned short*)&h1v;
                const unsigned short* h2p = (const unsigned short*)&h2v;
                float ho[4];
                #pragma unroll
                for (int reg = 0; reg < 4; ++reg) {
                    float rg = sig_pre(acc_r[rt][t][reg]);
                    float zg = sig_pre(acc_z[rt][t][reg]);
                    float cg = tanh_pre(acc_in[rt][t][reg] + rg * acc_hn[rt][t][reg]);
                    float hm = 0.5f * bf2f(h1p[reg]) + 0.5f * bf2f(h2p[reg]);
                    ho[reg] = (cg + zg * (hm - cg)) * m;
                }
                *(uint2*)(&hp[l15 * LDH + rt * 128 + u0]) = pack4(ho[0], ho[1], ho[2], ho[3]);
            }
        }
    }
    __syncthreads();

    // ---- parent M=16 ----
    {
        f32x4 acc_r[2], acc_z[2], acc_in[2], acc_hn[2];
        #pragma unroll
        for (int t = 0; t < 2; ++t) {
            acc_r[t] = b_r[t]; acc_z[t] = b_z[t]; acc_in[t] = b_in[t]; acc_hn[t] = b_hn[t];
        }
        #pragma unroll
        for (int t = 0; t < 2; ++t) {
            int tt = 2 * w + t;
            bf16x8 wr_ = *(const bf16x8*)(wFrag + ((size_t)(tt) * 64 + lane) * 8);
            bf16x8 wz_ = *(const bf16x8*)(wFrag + ((size_t)(8 + tt) * 64 + lane) * 8);
            bf16x8 wn_ = *(const bf16x8*)(wFrag + ((size_t)(16 + tt) * 64 + lane) * 8);
            acc_r[t] = mfma_wx(wr_, xp, acc_r[t]);
            acc_z[t] = mfma_wx(wz_, xp, acc_z[t]);
            acc_in[t] = mfma_wx(wn_, xp, acc_in[t]);
        }
        #pragma unroll 2
        for (int ks = 1; ks <= 8; ++ks) {
            bf16x8 a = *(const bf16x8*)(&hp[l15 * LDH + (ks - 1) * 32 + 8 * lg]);
            size_t fb = (size_t)ks * 24 * 64;
            #pragma unroll
            for (int t = 0; t < 2; ++t) {
                int tt = 2 * w + t;
                bf16x8 wr_ = *(const bf16x8*)(wFrag + (fb + (size_t)(tt) * 64 + lane) * 8);
                bf16x8 wz_ = *(const bf16x8*)(wFrag + (fb + (size_t)(8 + tt) * 64 + lane) * 8);
                bf16x8 wn_ = *(const bf16x8*)(wFrag + (fb + (size_t)(16 + tt) * 64 + lane) * 8);
                acc_r[t] = mfma_wx(wr_, a, acc_r[t]);
                acc_z[t] = mfma_wx(wz_, a, acc_z[t]);
                acc_hn[t] = mfma_wx(wn_, a, acc_hn[t]);
            }
        }
        float m = masks[pnode * B + (size_t)c8 * 16 + l15];
        #pragma unroll
        for (int t = 0; t < 2; ++t) {
            int u0 = w * 32 + t * 16 + lg * 4;
            ushort4 h1v = *(const ushort4*)(&hp[l15 * LDH + u0]);
            ushort4 h2v = *(const ushort4*)(&hp[l15 * LDH + 128 + u0]);
            const unsigned short* h1p = (const unsigned short*)&h1v;
            const unsigned short* h2p = (const unsigned short*)&h2v;
            float ho[4];
            #pragma unroll
            for (int reg = 0; reg < 4; ++reg) {
                float rg = sig_pre(acc_r[t][reg]);
                float zg = sig_pre(acc_z[t][reg]);
                float cg = tanh_pre(acc_in[t][reg] + rg * acc_hn[t][reg]);
                float hm = 0.5f * bf2f(h1p[reg]) + 0.5f * bf2f(h2p[reg]);
                ho[reg] = (cg + zg * (hm - cg)) * m;
            }
            uint2 pk = pack4(ho[0], ho[1], ho[2], ho[3]);
            *(uint2*)(outl + ((size_t)p * B + (size_t)c8 * 16 + l15) * H + u0) = pk;
            if (do_proj) *(uint2*)(&hp[l15 * LDH + u0]) = pk;
        }
    }

    if (do_proj) {
        __syncthreads();
        f32x4 pa[4];
        #pragma unroll
        for (int jj = 0; jj < 4; ++jj) {
            int ct2 = 4 * w + jj;
            int sel = ct2 >> 3, tl = ct2 & 7;
            pa[jj] = *(const f32x4*)(bias + 512 + sel * 128 + tl * 16 + lg * 4);
        }
        #pragma unroll
        for (int ks = 0; ks < 4; ++ks) {
            bf16x8 a = *(const bf16x8*)(&hp[l15 * LDH + ks * 32 + 8 * lg]);
            #pragma unroll
            for (int jj = 0; jj < 4; ++jj) {
                bf16x8 f = *(const bf16x8*)(pFrag + (((size_t)ks * 16 + 4 * w + jj) * 64 + lane) * 8);
                pa[jj] = mfma_wx(f, a, pa[jj]);
            }
        }
        #pragma unroll
        for (int jj = 0; jj < 4; ++jj) {
            int ct2 = 4 * w + jj;
            int sel = ct2 >> 3, tl = ct2 & 7;
            int u0 = tl * 16 + lg * 4;
            int row = c8 * 16 + l15;
            *(f32x4*)(proj_out + ((size_t)sel * B + row) * H + u0) = pa[jj];
        }
    }
}

// ---------------------------------------------------------------------------
extern "C" void kernel_launch(void* const* d_in, const int* in_sizes, int n_in,
                              void* d_out, int out_size, void* d_ws, size_t ws_size,
                              hipStream_t stream)
{
    const float* targets = (const float*)d_in[0];
    const float* masks   = (const float*)d_in[1];
    const float* wir_w = (const float*)d_in[2];  const float* wir_b = (const float*)d_in[3];
    const float* whr_w = (const float*)d_in[4];  const float* whr_b = (const float*)d_in[5];
    const float* wiz_w = (const float*)d_in[6];  const float* wiz_b = (const float*)d_in[7];
    const float* whz_w = (const float*)d_in[8];  const float* whz_b = (const float*)d_in[9];
    const float* win_w = (const float*)d_in[10]; const float* win_b = (const float*)d_in[11];
    const float* whn_w = (const float*)d_in[12]; const float* whn_b = (const float*)d_in[13];
    const float* mu_w  = (const float*)d_in[14]; const float* mu_b  = (const float*)d_in[15];
    const float* lv_w  = (const float*)d_in[16]; const float* lv_b  = (const float*)d_in[17];

    unsigned short* ws16 = (unsigned short*)d_ws;
    unsigned short* lvl8 = ws16;                               // 256*128*128
    unsigned short* lvl6 = lvl8 + (size_t)256 * B * H;         // 64*128*128
    unsigned short* lvl4 = lvl6 + (size_t)64 * B * H;          // 16*128*128
    unsigned short* lvl2 = lvl4 + (size_t)16 * B * H;          // 4*128*128
    unsigned short* lvl0 = lvl2 + (size_t)4 * B * H;           // 1*128*128
    unsigned short* wFrag = lvl0 + (size_t)1 * B * H;          // 110592 bf16
    unsigned short* pFrag = wFrag + 110592;                    // 32768 bf16
    float*          biasw = (float*)(pFrag + 32768);           // 768 fp32

    prep_pack<<<70, 256, 0, stream>>>(
        wir_w, whr_w, wiz_w, whz_w, win_w, whn_w,
        wir_b, whr_b, wiz_b, whz_b, win_b, whn_b,
        mu_w, mu_b, lv_w, lv_b, wFrag, pFrag, biasw);

    subtree8_kernel<<<1024, NTHR, 0, stream>>>(targets, masks, lvl8, wFrag, biasw);

    pair_kernel<<<512, NTHR, 0, stream>>>(targets, masks, 7, lvl8, lvl6, wFrag, biasw,
                                          0, nullptr, nullptr);
    pair_kernel<<<128, NTHR, 0, stream>>>(targets, masks, 5, lvl6, lvl4, wFrag, biasw,
                                          0, nullptr, nullptr);
    pair_kernel<<<32, NTHR, 0, stream>>>(targets, masks, 3, lvl4, lvl2, wFrag, biasw,
                                         0, nullptr, nullptr);
    pair_kernel<<<8, NTHR, 0, stream>>>(targets, masks, 1, lvl2, lvl0, wFrag, biasw,
                                        1, pFrag, (float*)d_out);
}

// Round 11
// 133.954 us; speedup vs baseline: 1.3347x; 1.3347x over previous
//
#include <hip/hip_runtime.h>
#include <hip/hip_bf16.h>
#include <math.h>

#define B 128
#define V 32
#define H 128
#define LDH 264    // h-region row pitch in bf16 elems (528 B)
#define NTHR 256

typedef __attribute__((ext_vector_type(8))) short bf16x8;
typedef __attribute__((ext_vector_type(4))) float f32x4;

// Swapped-operand layout: D = W_frag x Act_frag; lane owns batch row (lane&15)
// and 4 consecutive units ((lane>>4)*4 + reg).
__device__ inline f32x4 mfma_wx(bf16x8 wf, bf16x8 xf, f32x4 c) {
    return __builtin_amdgcn_mfma_f32_16x16x32_bf16(wf, xf, c, 0, 0, 0);
}
__device__ inline unsigned short f2bf(float f) {
    __hip_bfloat16 h = __float2bfloat16(f);
    return __builtin_bit_cast(unsigned short, h);
}
__device__ inline float bf2f(unsigned short u) {
    unsigned int x = ((unsigned int)u) << 16;
    return __builtin_bit_cast(float, x);
}
// pre-scaled activations: weights/biases for r,z carry -1/ln2, n carries 2/ln2
__device__ inline float sig_pre(float y)  { return __builtin_amdgcn_rcpf(1.f + __builtin_amdgcn_exp2f(y)); }
__device__ inline float tanh_pre(float y) { return 1.f - 2.f * __builtin_amdgcn_rcpf(__builtin_amdgcn_exp2f(y) + 1.f); }
__device__ inline bf16x8 load_xfrag(const float* p) {
    float4 a = *(const float4*)p;
    float4 b = *(const float4*)(p + 4);
    bf16x8 r;
    r[0] = (short)f2bf(a.x); r[1] = (short)f2bf(a.y);
    r[2] = (short)f2bf(a.z); r[3] = (short)f2bf(a.w);
    r[4] = (short)f2bf(b.x); r[5] = (short)f2bf(b.y);
    r[6] = (short)f2bf(b.z); r[7] = (short)f2bf(b.w);
    return r;
}
__device__ inline uint2 pack4(float a, float b, float c, float d) {
    uint2 r;
    r.x = (unsigned int)f2bf(a) | ((unsigned int)f2bf(b) << 16);
    r.y = (unsigned int)f2bf(c) | ((unsigned int)f2bf(d) << 16);
    return r;
}

// ---------------------------------------------------------------------------
// Pack GRU weights (PRE-SCALED) + proj weights into MFMA fragment order.
// ---------------------------------------------------------------------------
__global__ void prep_pack(const float* __restrict__ wir_w, const float* __restrict__ whr_w,
                          const float* __restrict__ wiz_w, const float* __restrict__ whz_w,
                          const float* __restrict__ win_w, const float* __restrict__ whn_w,
                          const float* __restrict__ wir_b, const float* __restrict__ whr_b,
                          const float* __restrict__ wiz_b, const float* __restrict__ whz_b,
                          const float* __restrict__ win_b, const float* __restrict__ whn_b,
                          const float* __restrict__ mu_w, const float* __restrict__ mu_b,
                          const float* __restrict__ lv_w, const float* __restrict__ lv_b,
                          unsigned short* __restrict__ wFrag, unsigned short* __restrict__ pFrag,
                          float* __restrict__ bias)
{
    int idx = blockIdx.x * blockDim.x + threadIdx.x;
    if (idx < 13824) {
        int lane = idx & 63;
        int ctks = idx >> 6;
        int ct = ctks % 24;
        int ks = ctks / 24;
        int g = ct >> 3;
        int t = ct & 7;
        int u = t * 16 + (lane & 15);
        const float scl = (g == 2) ? 2.88539008f : -1.44269504f;
        const float* wi = (g == 0) ? wir_w : (g == 1) ? wiz_w : win_w;
        const float* wh = (g == 0) ? whr_w : (g == 1) ? whz_w : whn_w;
        unsigned short v[8] __attribute__((aligned(16)));
        #pragma unroll
        for (int i = 0; i < 8; ++i) {
            float f;
            if (ks == 0) { int k = 8 * (lane >> 4) + i; f = wi[u * V + k]; }
            else         { int k = (ks - 1) * 32 + 8 * (lane >> 4) + i; f = wh[u * 256 + k]; }
            v[i] = f2bf(f * scl);
        }
        *(int4*)(wFrag + (size_t)idx * 8) = *(const int4*)v;
    } else if (idx < 13824 + 4096) {
        int pidx = idx - 13824;
        int lane = pidx & 63;
        int rest = pidx >> 6;
        int ct2 = rest & 15;
        int ks = rest >> 4;
        int sel = ct2 >> 3, tl = ct2 & 7;
        int u = tl * 16 + (lane & 15);
        const float* wsrc = sel ? lv_w : mu_w;
        unsigned short v[8] __attribute__((aligned(16)));
        #pragma unroll
        for (int i = 0; i < 8; ++i) {
            int k = ks * 32 + 8 * (lane >> 4) + i;
            v[i] = f2bf(wsrc[u * H + k]);
        }
        *(int4*)(pFrag + (size_t)pidx * 8) = *(const int4*)v;
    }
    if (idx < 6 * H) {
        int s = idx / H, u = idx % H;
        float val;
        if (s == 0)      val = (wir_b[u] + whr_b[u]) * -1.44269504f;
        else if (s == 1) val = (wiz_b[u] + whz_b[u]) * -1.44269504f;
        else if (s == 2) val = win_b[u] * 2.88539008f;
        else if (s == 3) val = whn_b[u] * 2.88539008f;
        else if (s == 4) val = mu_b[u];
        else             val = lv_b[u];
        bias[idx] = val;
    }
}

// ---------------------------------------------------------------------------
// Fused subtree kernel v2: levels leaf+9+8, spill-free (sequential unit-tile,
// acc = 8 f32x4, no weight-reg cache). Grid 1024: block (n = d8 node, q =
// 32-row chunk). lvl9 never touches HBM.
// ---------------------------------------------------------------------------
__global__ __launch_bounds__(NTHR, 4) void subtree8_kernel(
    const float* __restrict__ targets, const float* __restrict__ masks,
    unsigned short* __restrict__ lvl8,
    const unsigned short* __restrict__ wFrag, const float* __restrict__ bias)
{
    __shared__ __attribute__((aligned(16))) unsigned short h_lds[32 * LDH];   // leaf h of current d9 node
    __shared__ __attribute__((aligned(16))) unsigned short h2_lds[32 * LDH];  // d9 outputs [h(2n)|h(2n+1)]

    const int tid = threadIdx.x;
    const int lane = tid & 63;
    const int w = tid >> 6;
    const int l15 = lane & 15;
    const int lg = lane >> 4;
    const int n = blockIdx.x >> 2;
    const int q = blockIdx.x & 3;

    for (int half = 0; half < 2; ++half) {
        const int j = 2 * n + half;                         // d9 node
        const size_t r9 = (size_t)(511 + j) * B + (size_t)q * 32;

        // ---- leaf children of j -> h_lds (K0 only; h1=h2=0) ----
        for (int c = 0; c < 2; ++c) {
            const size_t crow = (size_t)(1023 + 2 * j + c) * B + (size_t)q * 32;
            bf16x8 xf0 = load_xfrag(targets + (crow + l15) * V + 8 * lg);
            bf16x8 xf1 = load_xfrag(targets + (crow + 16 + l15) * V + 8 * lg);
            float m0 = masks[crow + l15];
            float m1 = masks[crow + 16 + l15];
            #pragma unroll 1
            for (int t = 0; t < 2; ++t) {
                const int tt = 2 * w + t;
                const int u0 = w * 32 + t * 16 + lg * 4;
                f32x4 br4  = *(const f32x4*)(bias + u0);
                f32x4 bz4  = *(const f32x4*)(bias + 128 + u0);
                f32x4 bin4 = *(const f32x4*)(bias + 256 + u0);
                f32x4 bhn4 = *(const f32x4*)(bias + 384 + u0);
                bf16x8 wr_ = *(const bf16x8*)(wFrag + ((size_t)(tt) * 64 + lane) * 8);
                bf16x8 wz_ = *(const bf16x8*)(wFrag + ((size_t)(8 + tt) * 64 + lane) * 8);
                bf16x8 wn_ = *(const bf16x8*)(wFrag + ((size_t)(16 + tt) * 64 + lane) * 8);
                f32x4 ar0 = mfma_wx(wr_, xf0, br4);
                f32x4 ar1 = mfma_wx(wr_, xf1, br4);
                f32x4 az0 = mfma_wx(wz_, xf0, bz4);
                f32x4 az1 = mfma_wx(wz_, xf1, bz4);
                f32x4 an0 = mfma_wx(wn_, xf0, bin4);
                f32x4 an1 = mfma_wx(wn_, xf1, bin4);
                float ho[4];
                #pragma unroll
                for (int reg = 0; reg < 4; ++reg) {
                    float rg = sig_pre(ar0[reg]);
                    float zg = sig_pre(az0[reg]);
                    float cg = tanh_pre(an0[reg] + rg * bhn4[reg]);
                    ho[reg] = (cg - zg * cg) * m0;
                }
                *(uint2*)(&h_lds[l15 * LDH + c * 128 + u0]) = pack4(ho[0], ho[1], ho[2], ho[3]);
                #pragma unroll
                for (int reg = 0; reg < 4; ++reg) {
                    float rg = sig_pre(ar1[reg]);
                    float zg = sig_pre(az1[reg]);
                    float cg = tanh_pre(an1[reg] + rg * bhn4[reg]);
                    ho[reg] = (cg - zg * cg) * m1;
                }
                *(uint2*)(&h_lds[(16 + l15) * LDH + c * 128 + u0]) = pack4(ho[0], ho[1], ho[2], ho[3]);
            }
        }
        __syncthreads();   // h_lds (leaf h) ready

        // ---- d9 tile: K0 from x9, K1..8 from h_lds; out -> h2_lds ----
        {
            bf16x8 x9_0 = load_xfrag(targets + (r9 + l15) * V + 8 * lg);
            bf16x8 x9_1 = load_xfrag(targets + (r9 + 16 + l15) * V + 8 * lg);
            float m0 = masks[r9 + l15];
            float m1 = masks[r9 + 16 + l15];
            #pragma unroll 1
            for (int t = 0; t < 2; ++t) {
                const int tt = 2 * w + t;
                const int u0 = w * 32 + t * 16 + lg * 4;
                f32x4 acc_r0 = *(const f32x4*)(bias + u0);
                f32x4 acc_r1 = acc_r0;
                f32x4 acc_z0 = *(const f32x4*)(bias + 128 + u0);
                f32x4 acc_z1 = acc_z0;
                f32x4 acc_i0 = *(const f32x4*)(bias + 256 + u0);
                f32x4 acc_i1 = acc_i0;
                f32x4 acc_h0 = *(const f32x4*)(bias + 384 + u0);
                f32x4 acc_h1 = acc_h0;
                {
                    bf16x8 wr_ = *(const bf16x8*)(wFrag + ((size_t)(tt) * 64 + lane) * 8);
                    bf16x8 wz_ = *(const bf16x8*)(wFrag + ((size_t)(8 + tt) * 64 + lane) * 8);
                    bf16x8 wn_ = *(const bf16x8*)(wFrag + ((size_t)(16 + tt) * 64 + lane) * 8);
                    acc_r0 = mfma_wx(wr_, x9_0, acc_r0);
                    acc_r1 = mfma_wx(wr_, x9_1, acc_r1);
                    acc_z0 = mfma_wx(wz_, x9_0, acc_z0);
                    acc_z1 = mfma_wx(wz_, x9_1, acc_z1);
                    acc_i0 = mfma_wx(wn_, x9_0, acc_i0);
                    acc_i1 = mfma_wx(wn_, x9_1, acc_i1);
                }
                #pragma unroll 2
                for (int ks = 1; ks <= 8; ++ks) {
                    bf16x8 a0 = *(const bf16x8*)(&h_lds[l15 * LDH + (ks - 1) * 32 + 8 * lg]);
                    bf16x8 a1 = *(const bf16x8*)(&h_lds[(16 + l15) * LDH + (ks - 1) * 32 + 8 * lg]);
                    size_t fb = (size_t)ks * 24 * 64;
                    bf16x8 wr_ = *(const bf16x8*)(wFrag + (fb + (size_t)(tt) * 64 + lane) * 8);
                    bf16x8 wz_ = *(const bf16x8*)(wFrag + (fb + (size_t)(8 + tt) * 64 + lane) * 8);
                    bf16x8 wn_ = *(const bf16x8*)(wFrag + (fb + (size_t)(16 + tt) * 64 + lane) * 8);
                    acc_r0 = mfma_wx(wr_, a0, acc_r0);
                    acc_r1 = mfma_wx(wr_, a1, acc_r1);
                    acc_z0 = mfma_wx(wz_, a0, acc_z0);
                    acc_z1 = mfma_wx(wz_, a1, acc_z1);
                    acc_h0 = mfma_wx(wn_, a0, acc_h0);
                    acc_h1 = mfma_wx(wn_, a1, acc_h1);
                }
                // epilogue rt=0
                {
                    int row = l15;
                    ushort4 h1v = *(const ushort4*)(&h_lds[row * LDH + u0]);
                    ushort4 h2v = *(const ushort4*)(&h_lds[row * LDH + 128 + u0]);
                    const unsigned short* h1p = (const unsigned short*)&h1v;
                    const unsigned short* h2p = (const unsigned short*)&h2v;
                    float ho[4];
                    #pragma unroll
                    for (int reg = 0; reg < 4; ++reg) {
                        float rg = sig_pre(acc_r0[reg]);
                        float zg = sig_pre(acc_z0[reg]);
                        float cg = tanh_pre(acc_i0[reg] + rg * acc_h0[reg]);
                        float hm = 0.5f * bf2f(h1p[reg]) + 0.5f * bf2f(h2p[reg]);
                        ho[reg] = (cg + zg * (hm - cg)) * m0;
                    }
                    *(uint2*)(&h2_lds[row * LDH + half * 128 + u0]) = pack4(ho[0], ho[1], ho[2], ho[3]);
                }
                // epilogue rt=1
                {
                    int row = 16 + l15;
                    ushort4 h1v = *(const ushort4*)(&h_lds[row * LDH + u0]);
                    ushort4 h2v = *(const ushort4*)(&h_lds[row * LDH + 128 + u0]);
                    const unsigned short* h1p = (const unsigned short*)&h1v;
                    const unsigned short* h2p = (const unsigned short*)&h2v;
                    float ho[4];
                    #pragma unroll
                    for (int reg = 0; reg < 4; ++reg) {
                        float rg = sig_pre(acc_r1[reg]);
                        float zg = sig_pre(acc_z1[reg]);
                        float cg = tanh_pre(acc_i1[reg] + rg * acc_h1[reg]);
                        float hm = 0.5f * bf2f(h1p[reg]) + 0.5f * bf2f(h2p[reg]);
                        ho[reg] = (cg + zg * (hm - cg)) * m1;
                    }
                    *(uint2*)(&h2_lds[row * LDH + half * 128 + u0]) = pack4(ho[0], ho[1], ho[2], ho[3]);
                }
            }
        }
        __syncthreads();   // d9 reads of h_lds done; h2_lds writes visible
    }

    // ---- d8 tile: x8 + h2_lds -> global lvl8 ----
    {
        const size_t r8 = (size_t)(255 + n) * B + (size_t)q * 32;
        bf16x8 x8_0 = load_xfrag(targets + (r8 + l15) * V + 8 * lg);
        bf16x8 x8_1 = load_xfrag(targets + (r8 + 16 + l15) * V + 8 * lg);
        float m0 = masks[r8 + l15];
        float m1 = masks[r8 + 16 + l15];
        #pragma unroll 1
        for (int t = 0; t < 2; ++t) {
            const int tt = 2 * w + t;
            const int u0 = w * 32 + t * 16 + lg * 4;
            f32x4 acc_r0 = *(const f32x4*)(bias + u0);
            f32x4 acc_r1 = acc_r0;
            f32x4 acc_z0 = *(const f32x4*)(bias + 128 + u0);
            f32x4 acc_z1 = acc_z0;
            f32x4 acc_i0 = *(const f32x4*)(bias + 256 + u0);
            f32x4 acc_i1 = acc_i0;
            f32x4 acc_h0 = *(const f32x4*)(bias + 384 + u0);
            f32x4 acc_h1 = acc_h0;
            {
                bf16x8 wr_ = *(const bf16x8*)(wFrag + ((size_t)(tt) * 64 + lane) * 8);
                bf16x8 wz_ = *(const bf16x8*)(wFrag + ((size_t)(8 + tt) * 64 + lane) * 8);
                bf16x8 wn_ = *(const bf16x8*)(wFrag + ((size_t)(16 + tt) * 64 + lane) * 8);
                acc_r0 = mfma_wx(wr_, x8_0, acc_r0);
                acc_r1 = mfma_wx(wr_, x8_1, acc_r1);
                acc_z0 = mfma_wx(wz_, x8_0, acc_z0);
                acc_z1 = mfma_wx(wz_, x8_1, acc_z1);
                acc_i0 = mfma_wx(wn_, x8_0, acc_i0);
                acc_i1 = mfma_wx(wn_, x8_1, acc_i1);
            }
            #pragma unroll 2
            for (int ks = 1; ks <= 8; ++ks) {
                bf16x8 a0 = *(const bf16x8*)(&h2_lds[l15 * LDH + (ks - 1) * 32 + 8 * lg]);
                bf16x8 a1 = *(const bf16x8*)(&h2_lds[(16 + l15) * LDH + (ks - 1) * 32 + 8 * lg]);
                size_t fb = (size_t)ks * 24 * 64;
                bf16x8 wr_ = *(const bf16x8*)(wFrag + (fb + (size_t)(tt) * 64 + lane) * 8);
                bf16x8 wz_ = *(const bf16x8*)(wFrag + (fb + (size_t)(8 + tt) * 64 + lane) * 8);
                bf16x8 wn_ = *(const bf16x8*)(wFrag + (fb + (size_t)(16 + tt) * 64 + lane) * 8);
                acc_r0 = mfma_wx(wr_, a0, acc_r0);
                acc_r1 = mfma_wx(wr_, a1, acc_r1);
                acc_z0 = mfma_wx(wz_, a0, acc_z0);
                acc_z1 = mfma_wx(wz_, a1, acc_z1);
                acc_h0 = mfma_wx(wn_, a0, acc_h0);
                acc_h1 = mfma_wx(wn_, a1, acc_h1);
            }
            #pragma unroll
            for (int rt = 0; rt < 2; ++rt) {
                int row = rt * 16 + l15;
                float m = rt ? m1 : m0;
                ushort4 h1v = *(const ushort4*)(&h2_lds[row * LDH + u0]);
                ushort4 h2v = *(const ushort4*)(&h2_lds[row * LDH + 128 + u0]);
                const unsigned short* h1p = (const unsigned short*)&h1v;
                const unsigned short* h2p = (const unsigned short*)&h2v;
                f32x4 ar = rt ? acc_r1 : acc_r0;
                f32x4 az = rt ? acc_z1 : acc_z0;
                f32x4 ai = rt ? acc_i1 : acc_i0;
                f32x4 ah = rt ? acc_h1 : acc_h0;
                float ho[4];
                #pragma unroll
                for (int reg = 0; reg < 4; ++reg) {
                    float rg = sig_pre(ar[reg]);
                    float zg = sig_pre(az[reg]);
                    float cg = tanh_pre(ai[reg] + rg * ah[reg]);
                    float hm = 0.5f * bf2f(h1p[reg]) + 0.5f * bf2f(h2p[reg]);
                    ho[reg] = (cg + zg * (hm - cg)) * m;
                }
                *(uint2*)(lvl8 + ((size_t)n * B + (size_t)q * 32 + row) * H + u0) =
                    pack4(ho[0], ho[1], ho[2], ho[3]);
            }
        }
    }
}

// ---------------------------------------------------------------------------
// Pair kernel: (du, dl=du-1) + optional fused projection at dl==0. (unchanged)
// ---------------------------------------------------------------------------
__global__ __launch_bounds__(NTHR, 4) void pair_kernel(
    const float* __restrict__ targets, const float* __restrict__ masks,
    int du,
    const unsigned short* __restrict__ prev,
    unsigned short* __restrict__ outl,
    const unsigned short* __restrict__ wFrag, const float* __restrict__ bias,
    int do_proj, const unsigned short* __restrict__ pFrag, float* __restrict__ proj_out)
{
    __shared__ __attribute__((aligned(16))) unsigned short hc[32 * LDH];
    __shared__ __attribute__((aligned(16))) unsigned short hp[16 * LDH];

    const int tid = threadIdx.x;
    const int lane = tid & 63;
    const int w = tid >> 6;
    const int l15 = lane & 15;
    const int lg = lane >> 4;
    const int p = blockIdx.x >> 3;
    const int c8 = blockIdx.x & 7;
    const int dl = du - 1;

    #pragma unroll
    for (int t = 0; t < 4; ++t) {
        int task = t * NTHR + tid;
        int row = task >> 5;
        int ck = task & 31;
        int gnode = 4 * p + ((row >> 4) << 1) + (ck >> 4);
        int4 v = *(const int4*)(prev + (((size_t)gnode) * B + (size_t)c8 * 16 + (row & 15)) * H + (ck & 15) * 8);
        *(int4*)(&hc[row * LDH + ck * 8]) = v;
    }
    const size_t cbase = (size_t)((1 << du) - 1) + 2 * p;
    bf16x8 xc0 = load_xfrag(targets + ((cbase) * B + (size_t)c8 * 16 + l15) * V + 8 * lg);
    bf16x8 xc1 = load_xfrag(targets + ((cbase + 1) * B + (size_t)c8 * 16 + l15) * V + 8 * lg);
    const size_t pnode = (size_t)((1 << dl) - 1) + p;
    bf16x8 xp = load_xfrag(targets + (pnode * B + (size_t)c8 * 16 + l15) * V + 8 * lg);

    f32x4 b_r[2], b_z[2], b_in[2], b_hn[2];
    #pragma unroll
    for (int t = 0; t < 2; ++t) {
        int u0 = w * 32 + t * 16 + lg * 4;
        b_r[t]  = *(const f32x4*)(bias + u0);
        b_z[t]  = *(const f32x4*)(bias + 128 + u0);
        b_in[t] = *(const f32x4*)(bias + 256 + u0);
        b_hn[t] = *(const f32x4*)(bias + 384 + u0);
    }
    __syncthreads();

    // ---- children (rt = child index, 16 rows each) ----
    {
        f32x4 acc_r[2][2], acc_z[2][2], acc_in[2][2], acc_hn[2][2];
        #pragma unroll
        for (int t = 0; t < 2; ++t) {
            acc_r[0][t] = b_r[t];   acc_r[1][t] = b_r[t];
            acc_z[0][t] = b_z[t];   acc_z[1][t] = b_z[t];
            acc_in[0][t] = b_in[t]; acc_in[1][t] = b_in[t];
            acc_hn[0][t] = b_hn[t]; acc_hn[1][t] = b_hn[t];
        }
        #pragma unroll
        for (int t = 0; t < 2; ++t) {
            int tt = 2 * w + t;
            bf16x8 wr_ = *(const bf16x8*)(wFrag + ((size_t)(tt) * 64 + lane) * 8);
            bf16x8 wz_ = *(const bf16x8*)(wFrag + ((size_t)(8 + tt) * 64 + lane) * 8);
            bf16x8 wn_ = *(const bf16x8*)(wFrag + ((size_t)(16 + tt) * 64 + lane) * 8);
            acc_r[0][t] = mfma_wx(wr_, xc0, acc_r[0][t]);
            acc_r[1][t] = mfma_wx(wr_, xc1, acc_r[1][t]);
            acc_z[0][t] = mfma_wx(wz_, xc0, acc_z[0][t]);
            acc_z[1][t] = mfma_wx(wz_, xc1, acc_z[1][t]);
            acc_in[0][t] = mfma_wx(wn_, xc0, acc_in[0][t]);
            acc_in[1][t] = mfma_wx(wn_, xc1, acc_in[1][t]);
        }
        #pragma unroll 2
        for (int ks = 1; ks <= 8; ++ks) {
            bf16x8 a0 = *(const bf16x8*)(&hc[l15 * LDH + (ks - 1) * 32 + 8 * lg]);
            bf16x8 a1 = *(const bf16x8*)(&hc[(16 + l15) * LDH + (ks - 1) * 32 + 8 * lg]);
            size_t fb = (size_t)ks * 24 * 64;
            #pragma unroll
            for (int t = 0; t < 2; ++t) {
                int tt = 2 * w + t;
                bf16x8 wr_ = *(const bf16x8*)(wFrag + (fb + (size_t)(tt) * 64 + lane) * 8);
                bf16x8 wz_ = *(const bf16x8*)(wFrag + (fb + (size_t)(8 + tt) * 64 + lane) * 8);
                bf16x8 wn_ = *(const bf16x8*)(wFrag + (fb + (size_t)(16 + tt) * 64 + lane) * 8);
                acc_r[0][t] = mfma_wx(wr_, a0, acc_r[0][t]);
                acc_r[1][t] = mfma_wx(wr_, a1, acc_r[1][t]);
                acc_z[0][t] = mfma_wx(wz_, a0, acc_z[0][t]);
                acc_z[1][t] = mfma_wx(wz_, a1, acc_z[1][t]);
                acc_hn[0][t] = mfma_wx(wn_, a0, acc_hn[0][t]);
                acc_hn[1][t] = mfma_wx(wn_, a1, acc_hn[1][t]);
            }
        }
        #pragma unroll
        for (int rt = 0; rt < 2; ++rt) {
            float m = masks[(cbase + rt) * B + (size_t)c8 * 16 + l15];
            int hrow = rt * 16 + l15;
            #pragma unroll
            for (int t = 0; t < 2; ++t) {
                int u0 = w * 32 + t * 16 + lg * 4;
                ushort4 h1v = *(const ushort4*)(&hc[hrow * LDH + u0]);
                ushort4 h2v = *(const ushort4*)(&hc[hrow * LDH + 128 + u0]);
                const unsigned short* h1p = (const unsigned short*)&h1v;
                const unsigned short* h2p = (const unsigned short*)&h2v;
                float ho[4];
                #pragma unroll
                for (int reg = 0; reg < 4; ++reg) {
                    float rg = sig_pre(acc_r[rt][t][reg]);
                    float zg = sig_pre(acc_z[rt][t][reg]);
                    float cg = tanh_pre(acc_in[rt][t][reg] + rg * acc_hn[rt][t][reg]);
                    float hm = 0.5f * bf2f(h1p[reg]) + 0.5f * bf2f(h2p[reg]);
                    ho[reg] = (cg + zg * (hm - cg)) * m;
                }
                *(uint2*)(&hp[l15 * LDH + rt * 128 + u0]) = pack4(ho[0], ho[1], ho[2], ho[3]);
            }
        }
    }
    __syncthreads();

    // ---- parent M=16 ----
    {
        f32x4 acc_r[2], acc_z[2], acc_in[2], acc_hn[2];
        #pragma unroll
        for (int t = 0; t < 2; ++t) {
            acc_r[t] = b_r[t]; acc_z[t] = b_z[t]; acc_in[t] = b_in[t]; acc_hn[t] = b_hn[t];
        }
        #pragma unroll
        for (int t = 0; t < 2; ++t) {
            int tt = 2 * w + t;
            bf16x8 wr_ = *(const bf16x8*)(wFrag + ((size_t)(tt) * 64 + lane) * 8);
            bf16x8 wz_ = *(const bf16x8*)(wFrag + ((size_t)(8 + tt) * 64 + lane) * 8);
            bf16x8 wn_ = *(const bf16x8*)(wFrag + ((size_t)(16 + tt) * 64 + lane) * 8);
            acc_r[t] = mfma_wx(wr_, xp, acc_r[t]);
            acc_z[t] = mfma_wx(wz_, xp, acc_z[t]);
            acc_in[t] = mfma_wx(wn_, xp, acc_in[t]);
        }
        #pragma unroll 2
        for (int ks = 1; ks <= 8; ++ks) {
            bf16x8 a = *(const bf16x8*)(&hp[l15 * LDH + (ks - 1) * 32 + 8 * lg]);
            size_t fb = (size_t)ks * 24 * 64;
            #pragma unroll
            for (int t = 0; t < 2; ++t) {
                int tt = 2 * w + t;
                bf16x8 wr_ = *(const bf16x8*)(wFrag + (fb + (size_t)(tt) * 64 + lane) * 8);
                bf16x8 wz_ = *(const bf16x8*)(wFrag + (fb + (size_t)(8 + tt) * 64 + lane) * 8);
                bf16x8 wn_ = *(const bf16x8*)(wFrag + (fb + (size_t)(16 + tt) * 64 + lane) * 8);
                acc_r[t] = mfma_wx(wr_, a, acc_r[t]);
                acc_z[t] = mfma_wx(wz_, a, acc_z[t]);
                acc_hn[t] = mfma_wx(wn_, a, acc_hn[t]);
            }
        }
        float m = masks[pnode * B + (size_t)c8 * 16 + l15];
        #pragma unroll
        for (int t = 0; t < 2; ++t) {
            int u0 = w * 32 + t * 16 + lg * 4;
            ushort4 h1v = *(const ushort4*)(&hp[l15 * LDH + u0]);
            ushort4 h2v = *(const ushort4*)(&hp[l15 * LDH + 128 + u0]);
            const unsigned short* h1p = (const unsigned short*)&h1v;
            const unsigned short* h2p = (const unsigned short*)&h2v;
            float ho[4];
            #pragma unroll
            for (int reg = 0; reg < 4; ++reg) {
                float rg = sig_pre(acc_r[t][reg]);
                float zg = sig_pre(acc_z[t][reg]);
                float cg = tanh_pre(acc_in[t][reg] + rg * acc_hn[t][reg]);
                float hm = 0.5f * bf2f(h1p[reg]) + 0.5f * bf2f(h2p[reg]);
                ho[reg] = (cg + zg * (hm - cg)) * m;
            }
            uint2 pk = pack4(ho[0], ho[1], ho[2], ho[3]);
            *(uint2*)(outl + ((size_t)p * B + (size_t)c8 * 16 + l15) * H + u0) = pk;
            if (do_proj) *(uint2*)(&hp[l15 * LDH + u0]) = pk;
        }
    }

    if (do_proj) {
        __syncthreads();
        f32x4 pa[4];
        #pragma unroll
        for (int jj = 0; jj < 4; ++jj) {
            int ct2 = 4 * w + jj;
            int sel = ct2 >> 3, tl = ct2 & 7;
            pa[jj] = *(const f32x4*)(bias + 512 + sel * 128 + tl * 16 + lg * 4);
        }
        #pragma unroll
        for (int ks = 0; ks < 4; ++ks) {
            bf16x8 a = *(const bf16x8*)(&hp[l15 * LDH + ks * 32 + 8 * lg]);
            #pragma unroll
            for (int jj = 0; jj < 4; ++jj) {
                bf16x8 f = *(const bf16x8*)(pFrag + (((size_t)ks * 16 + 4 * w + jj) * 64 + lane) * 8);
                pa[jj] = mfma_wx(f, a, pa[jj]);
            }
        }
        #pragma unroll
        for (int jj = 0; jj < 4; ++jj) {
            int ct2 = 4 * w + jj;
            int sel = ct2 >> 3, tl = ct2 & 7;
            int u0 = tl * 16 + lg * 4;
            int row = c8 * 16 + l15;
            *(f32x4*)(proj_out + ((size_t)sel * B + row) * H + u0) = pa[jj];
        }
    }
}

// ---------------------------------------------------------------------------
extern "C" void kernel_launch(void* const* d_in, const int* in_sizes, int n_in,
                              void* d_out, int out_size, void* d_ws, size_t ws_size,
                              hipStream_t stream)
{
    const float* targets = (const float*)d_in[0];
    const float* masks   = (const float*)d_in[1];
    const float* wir_w = (const float*)d_in[2];  const float* wir_b = (const float*)d_in[3];
    const float* whr_w = (const float*)d_in[4];  const float* whr_b = (const float*)d_in[5];
    const float* wiz_w = (const float*)d_in[6];  const float* wiz_b = (const float*)d_in[7];
    const float* whz_w = (const float*)d_in[8];  const float* whz_b = (const float*)d_in[9];
    const float* win_w = (const float*)d_in[10]; const float* win_b = (const float*)d_in[11];
    const float* whn_w = (const float*)d_in[12]; const float* whn_b = (const float*)d_in[13];
    const float* mu_w  = (const float*)d_in[14]; const float* mu_b  = (const float*)d_in[15];
    const float* lv_w  = (const float*)d_in[16]; const float* lv_b  = (const float*)d_in[17];

    unsigned short* ws16 = (unsigned short*)d_ws;
    unsigned short* lvl8 = ws16;                               // 256*128*128
    unsigned short* lvl6 = lvl8 + (size_t)256 * B * H;         // 64*128*128
    unsigned short* lvl4 = lvl6 + (size_t)64 * B * H;          // 16*128*128
    unsigned short* lvl2 = lvl4 + (size_t)16 * B * H;          // 4*128*128
    unsigned short* lvl0 = lvl2 + (size_t)4 * B * H;           // 1*128*128
    unsigned short* wFrag = lvl0 + (size_t)1 * B * H;          // 110592 bf16
    unsigned short* pFrag = wFrag + 110592;                    // 32768 bf16
    float*          biasw = (float*)(pFrag + 32768);           // 768 fp32

    prep_pack<<<70, 256, 0, stream>>>(
        wir_w, whr_w, wiz_w, whz_w, win_w, whn_w,
        wir_b, whr_b, wiz_b, whz_b, win_b, whn_b,
        mu_w, mu_b, lv_w, lv_b, wFrag, pFrag, biasw);

    subtree8_kernel<<<1024, NTHR, 0, stream>>>(targets, masks, lvl8, wFrag, biasw);

    pair_kernel<<<512, NTHR, 0, stream>>>(targets, masks, 7, lvl8, lvl6, wFrag, biasw,
                                          0, nullptr, nullptr);
    pair_kernel<<<128, NTHR, 0, stream>>>(targets, masks, 5, lvl6, lvl4, wFrag, biasw,
                                          0, nullptr, nullptr);
    pair_kernel<<<32, NTHR, 0, stream>>>(targets, masks, 3, lvl4, lvl2, wFrag, biasw,
                                         0, nullptr, nullptr);
    pair_kernel<<<8, NTHR, 0, stream>>>(targets, masks, 1, lvl2, lvl0, wFrag, biasw,
                                        1, pFrag, (float*)d_out);
}